// Round 2
// baseline (93.033 us; speedup 1.0000x reference)
//
#include <hip/hip_runtime.h>

typedef unsigned short u16;
typedef unsigned int u32;
typedef __bf16 bf16x8 __attribute__((ext_vector_type(8)));
typedef float f32x4 __attribute__((ext_vector_type(4)));

// Prepped-weight layout in g_wbuf (bytes), rewritten fully by prep_kernel
// every launch (deterministic — same inputs, same values):
//   W1f @ 0      : 7kt*10nt*64lane*8elem u16 = 71680 B  (K 200->224, N 150->160, zero-padded)
//   W2f @ 71680  : 5kt*7nt*64lane*8elem u16  = 35840 B  (K 150->160, N 100->112, zero-padded)
//   b1p @ 107520 : 160 f32 (zero-padded)
//   b2p @ 108160 : 112 f32 (zero-padded)
#define W2F_OFF 71680
#define B1_OFF 107520
#define B2_OFF 108160
#define WS_BYTES 108608

__device__ __align__(256) unsigned char g_wbuf[WS_BYTES];

__device__ __forceinline__ u16 f2bf(float f) {
  u32 u = __builtin_bit_cast(u32, f);
  u = (u + 0x7FFFu + ((u >> 16) & 1u)) >> 16;  // RNE
  return (u16)u;
}

__global__ void prep_kernel(const float* __restrict__ W1, const float* __restrict__ b1,
                            const float* __restrict__ W2, const float* __restrict__ b2)
{
  const int stride = gridDim.x * blockDim.x;
  const int tid0 = blockIdx.x * blockDim.x + threadIdx.x;
  u16* w1f = (u16*)g_wbuf;
  for (int e = tid0; e < 35840; e += stride) {
    int j = e & 7, l = (e >> 3) & 63, nt = (e >> 9) % 10, kt = e / 5120;
    int k = kt * 32 + ((l >> 4) << 3) + j;
    int n = nt * 16 + (l & 15);
    w1f[e] = (k < 200 && n < 150) ? f2bf(W1[k * 150 + n]) : (u16)0;
  }
  u16* w2f = (u16*)(g_wbuf + W2F_OFF);
  for (int e = tid0; e < 17920; e += stride) {
    int j = e & 7, l = (e >> 3) & 63, nt = (e >> 9) % 7, kt = e / 3584;
    int k = kt * 32 + ((l >> 4) << 3) + j;
    int n = nt * 16 + (l & 15);
    w2f[e] = (k < 150 && n < 100) ? f2bf(W2[k * 100 + n]) : (u16)0;
  }
  float* b1p = (float*)(g_wbuf + B1_OFF);
  for (int e = tid0; e < 160; e += stride) b1p[e] = (e < 150) ? b1[e] : 0.f;
  float* b2p = (float*)(g_wbuf + B2_OFF);
  for (int e = tid0; e < 112; e += stride) b2p[e] = (e < 100) ? b2[e] : 0.f;
}

// BM=128 rows/block, 256 threads (4 waves), wave w owns m-tiles {w, w+4}.
// LDS: xs only, 57344 B -> 2 blocks/CU. B-fragments read straight from
// global (L2-resident). Exactly 3 barriers, no concurrent LDS read/write.
__global__ __launch_bounds__(256, 2)
void fused_mlp(const float* __restrict__ x, float* __restrict__ out, int B)
{
  __shared__ __align__(16) u16 xs[28672];

  const int tid = threadIdx.x;
  const int lane = tid & 63;
  const int wv = tid >> 6;
  const int cl = lane & 15, gr = lane >> 4;
  const long r0 = (long)blockIdx.x * 128;

  // ---- stage x tile: f32 coalesced (fully contiguous) -> bf16 A-frags ----
  const float* xg = x + r0 * 200;
  #pragma unroll
  for (int i = 0; i < 25; ++i) {
    int c = tid + i * 256;            // 128 rows * 50 float4-chunks
    int row = c / 50, kc = c % 50;
    float4 v = *reinterpret_cast<const float4*>(xg + row * 200 + kc * 4);
    int k0 = kc * 4;
    int fl = (row & 15) | (((k0 & 31) >> 3) << 4);
    int idx = (((row >> 4) * 7 + (k0 >> 5)) * 64 + fl) * 8 + (k0 & 7);
    uint2 p;
    p.x = (u32)f2bf(v.x) | ((u32)f2bf(v.y) << 16);
    p.y = (u32)f2bf(v.z) | ((u32)f2bf(v.w) << 16);
    *reinterpret_cast<uint2*>(&xs[idx]) = p;
  }
  // zero k-pad (k=200..223): kt=6 fragment lanes 16..63
  #pragma unroll
  for (int i = 0; i < 3; ++i) {
    int pidx = tid + i * 256;         // 8 mt * 48 lanes * 2 halves = 768
    int mt = pidx / 96, rem = pidx % 96;
    int fl = 16 + (rem >> 1);
    int idx = ((mt * 7 + 6) * 64 + fl) * 8 + (rem & 1) * 4;
    uint2 z; z.x = 0u; z.y = 0u;
    *reinterpret_cast<uint2*>(&xs[idx]) = z;
  }
  __syncthreads();   // (1) xs fully staged before any A-frag read

  const int mt0 = wv, mt1 = wv + 4;
  const u16* w1g = (const u16*)g_wbuf;
  const u16* w2g = (const u16*)(g_wbuf + W2F_OFF);

  const f32x4 zz = {0.f, 0.f, 0.f, 0.f};
  f32x4 acc1[2][10];
  #pragma unroll
  for (int i = 0; i < 2; ++i)
    #pragma unroll
    for (int nt = 0; nt < 10; ++nt) acc1[i][nt] = zz;

  // ---- GEMM1: [128 x 224] @ [224 x 160], B-frags direct from global ----
  #pragma unroll
  for (int kt = 0; kt < 7; ++kt) {
    bf16x8 bfr[10];
    #pragma unroll
    for (int nt = 0; nt < 10; ++nt)
      bfr[nt] = *reinterpret_cast<const bf16x8*>(w1g + ((kt * 10 + nt) * 64 + lane) * 8);
    bf16x8 a0 = *reinterpret_cast<const bf16x8*>(&xs[((mt0 * 7 + kt) * 64 + lane) * 8]);
    bf16x8 a1 = *reinterpret_cast<const bf16x8*>(&xs[((mt1 * 7 + kt) * 64 + lane) * 8]);
    #pragma unroll
    for (int nt = 0; nt < 10; ++nt) {
      acc1[0][nt] = __builtin_amdgcn_mfma_f32_16x16x32_bf16(a0, bfr[nt], acc1[0][nt], 0, 0, 0);
      acc1[1][nt] = __builtin_amdgcn_mfma_f32_16x16x32_bf16(a1, bfr[nt], acc1[1][nt], 0, 0, 0);
    }
  }
  __syncthreads();   // (2) all GEMM1 A-frag reads done before h1 overwrites xs

  // ---- epilogue 1: bias + leaky, out1 row-means, h1 -> xs as GEMM2 A-frags ----
  const float* b1p = (const float*)(g_wbuf + B1_OFF);
  float b1v[10];
  #pragma unroll
  for (int nt = 0; nt < 10; ++nt) b1v[nt] = b1p[nt * 16 + cl];

  float rs0[4] = {0, 0, 0, 0}, rs1[4] = {0, 0, 0, 0};
  #pragma unroll
  for (int nt = 0; nt < 10; ++nt) {
    int k2 = nt * 16 + cl;              // h1 column = GEMM2 k index
    int kt2 = k2 >> 5;
    int l2base = 16 * ((k2 & 31) >> 3);
    int e2 = k2 & 7;
    #pragma unroll
    for (int j = 0; j < 4; ++j) {
      int m = gr * 4 + j;               // C/D: row=(lane>>4)*4+reg, col=lane&15
      int l2 = m + l2base;
      float h = acc1[0][nt][j] + b1v[nt];
      h = (h >= 0.f) ? h : 0.1f * h;
      rs0[j] += h;
      xs[((mt0 * 5 + kt2) * 64 + l2) * 8 + e2] = f2bf(h);
      float g = acc1[1][nt][j] + b1v[nt];
      g = (g >= 0.f) ? g : 0.1f * g;
      rs1[j] += g;
      xs[((mt1 * 5 + kt2) * 64 + l2) * 8 + e2] = f2bf(g);
    }
  }
  #pragma unroll
  for (int j = 0; j < 4; ++j) {
    float s0 = rs0[j], s1 = rs1[j];
    #pragma unroll
    for (int mask = 1; mask < 16; mask <<= 1) {
      s0 += __shfl_xor(s0, mask, 64);
      s1 += __shfl_xor(s1, mask, 64);
    }
    if (cl == 0) {
      out[r0 + mt0 * 16 + gr * 4 + j] = s0 * (1.f / 150.f);
      out[r0 + mt1 * 16 + gr * 4 + j] = s1 * (1.f / 150.f);
    }
  }
  __syncthreads();   // (3) h1 frags fully written before GEMM2 reads

  // ---- GEMM2: [128 x 160] @ [160 x 112] ----
  f32x4 acc2[2][7];
  #pragma unroll
  for (int i = 0; i < 2; ++i)
    #pragma unroll
    for (int nt = 0; nt < 7; ++nt) acc2[i][nt] = zz;

  #pragma unroll
  for (int kt = 0; kt < 5; ++kt) {
    bf16x8 bfr[7];
    #pragma unroll
    for (int nt = 0; nt < 7; ++nt)
      bfr[nt] = *reinterpret_cast<const bf16x8*>(w2g + ((kt * 7 + nt) * 64 + lane) * 8);
    bf16x8 a0 = *reinterpret_cast<const bf16x8*>(&xs[((mt0 * 5 + kt) * 64 + lane) * 8]);
    bf16x8 a1 = *reinterpret_cast<const bf16x8*>(&xs[((mt1 * 5 + kt) * 64 + lane) * 8]);
    #pragma unroll
    for (int nt = 0; nt < 7; ++nt) {
      acc2[0][nt] = __builtin_amdgcn_mfma_f32_16x16x32_bf16(a0, bfr[nt], acc2[0][nt], 0, 0, 0);
      acc2[1][nt] = __builtin_amdgcn_mfma_f32_16x16x32_bf16(a1, bfr[nt], acc2[1][nt], 0, 0, 0);
    }
  }

  // ---- epilogue 2: bias + leaky, out2 row-means (padded cols contribute 0) ----
  const float* b2p = (const float*)(g_wbuf + B2_OFF);
  float b2v[7];
  #pragma unroll
  for (int nt = 0; nt < 7; ++nt) b2v[nt] = b2p[nt * 16 + cl];

  float t0[4] = {0, 0, 0, 0}, t1[4] = {0, 0, 0, 0};
  #pragma unroll
  for (int nt = 0; nt < 7; ++nt) {
    #pragma unroll
    for (int j = 0; j < 4; ++j) {
      float h = acc2[0][nt][j] + b2v[nt];
      h = (h >= 0.f) ? h : 0.1f * h;
      t0[j] += h;
      float g = acc2[1][nt][j] + b2v[nt];
      g = (g >= 0.f) ? g : 0.1f * g;
      t1[j] += g;
    }
  }
  #pragma unroll
  for (int j = 0; j < 4; ++j) {
    float s0 = t0[j], s1 = t1[j];
    #pragma unroll
    for (int mask = 1; mask < 16; mask <<= 1) {
      s0 += __shfl_xor(s0, mask, 64);
      s1 += __shfl_xor(s1, mask, 64);
    }
    if (cl == 0) {
      out[B + r0 + mt0 * 16 + gr * 4 + j] = s0 * (1.f / 100.f);
      out[B + r0 + mt1 * 16 + gr * 4 + j] = s1 * (1.f / 100.f);
    }
  }
}

extern "C" void kernel_launch(void* const* d_in, const int* in_sizes, int n_in,
                              void* d_out, int out_size, void* d_ws, size_t ws_size,
                              hipStream_t stream)
{
  const float* x  = (const float*)d_in[0];
  const float* W1 = (const float*)d_in[1];
  const float* b1 = (const float*)d_in[2];
  const float* W2 = (const float*)d_in[3];
  const float* b2 = (const float*)d_in[4];
  float* out = (float*)d_out;
  const int B = in_sizes[0] / 200;   // 262144

  prep_kernel<<<64, 256, 0, stream>>>(W1, b1, W2, b2);
  fused_mlp<<<B / 128, 256, 0, stream>>>(x, out, B);
}